// Round 1
// baseline (386.795 us; speedup 1.0000x reference)
//
#include <hip/hip_runtime.h>

#define HH 51
#define TT 256
#define NB 16
#define L2E 1.442695041f

typedef __attribute__((ext_vector_type(8))) _Float16 half8;
typedef __attribute__((ext_vector_type(4))) float   floatx4;

#define MFMA16F(A,B,C) __builtin_amdgcn_mfma_f32_16x16x32_f16((A),(B),(C),0,0,0)

__device__ __forceinline__ float rcp_fast(float x) { return __builtin_amdgcn_rcpf(x); }
#if __has_builtin(__builtin_amdgcn_exp2f)
__device__ __forceinline__ float exp2_fast(float x) { return __builtin_amdgcn_exp2f(x); }
#else
__device__ __forceinline__ float exp2_fast(float x) { return __expf(0.69314718056f * x); }
#endif
__device__ __forceinline__ unsigned short f2h_bits(float v) {
    return __builtin_bit_cast(unsigned short, (_Float16)v);
}

// ------------- weight pre-pack: fp16 hi/lo fragments, K-column folding ---
// (UNCHANGED from the 377us version; layout comments there still apply.)
__global__ void lstm_prep(const float* __restrict__ Whh1, const float* __restrict__ Wih1,
                          const float* __restrict__ bih1, const float* __restrict__ bhh1,
                          const float* __restrict__ Wih2, const float* __restrict__ Whh2,
                          const float* __restrict__ bih2, const float* __restrict__ bhh2,
                          const float* __restrict__ Wlin, const float* __restrict__ blin,
                          uint4* __restrict__ frags) {
    int tid = blockIdx.x * blockDim.x + threadIdx.x;
    if (tid >= 196 * 64) return;
    int f = tid >> 6, lane = tid & 63;
    int n = lane & 15, qq = lane >> 4;
    int hl, s, tau, cell;
    if (f < 64)       { cell = 1; int r = f;       hl = r & 1; r >>= 1; s = r & 1; tau = r >> 1; }
    else if (f < 192) { cell = 2; int r = f - 64;  hl = r & 1; r >>= 1; s = r & 3; tau = r >> 2; }
    else              { cell = 3; int r = f - 192; hl = r & 1; s = r >> 1; tau = 0; }
    int g = tau >> 2, U = tau & 3, u = U * 16 + n;
    float sc = (cell == 3) ? 1.0f : ((g == 2) ? 2.0f * L2E : L2E);
    unsigned int dw[4];
    for (int d = 0; d < 4; d++) {
        unsigned int packed = 0;
        for (int e = 0; e < 2; e++) {
            int jj = d * 2 + e;
            int k = s * 32 + qq * 8 + jj;
            float val = 0.f;
            if (cell == 1) {
                if (u < HH) {
                    if (k < HH)       val = Whh1[(g * HH + u) * HH + k];
                    else if (k == 51) val = bih1[g * HH + u] + bhh1[g * HH + u];
                    else              val = Wih1[g * HH + u];   // k=52,53
                }
            } else if (cell == 2) {
                if (u < HH) {
                    if (k < 64) {
                        if (k < HH)       val = Wih2[(g * HH + u) * HH + k];
                        else if (k == 51) val = bih2[g * HH + u] + bhh2[g * HH + u];
                        // k=52,53 stay 0 (x pass-through)
                    } else {
                        int k2 = k - 64;
                        if (k2 < HH) val = Whh2[(g * HH + u) * HH + k2];
                    }
                }
            } else {
                if (n == 0) {
                    if (k < HH)       val = Wlin[k];
                    else if (k == 51) val = blin[0];
                }
            }
            val *= sc;
            _Float16 hi = (_Float16)val;
            unsigned short bits;
            if (hl) { float lo = val - (float)hi; bits = f2h_bits(lo); }
            else    { bits = __builtin_bit_cast(unsigned short, hi); }
            packed |= ((unsigned int)bits) << (16 * e);
        }
        dw[d] = packed;
    }
    frags[f * 64 + lane] = make_uint4(dw[0], dw[1], dw[2], dw[3]);
}

// ---- producer/consumer flag sync (replaces the per-step s_barrier) ------
// Counters count wave-step completions (x4 per group step). Monotonic;
// all 8 waves of a block are co-resident on one CU, so spinning is safe.
__device__ __forceinline__ void wait_ge(int* c, int tgt) {
    if (__hip_atomic_load(c, __ATOMIC_ACQUIRE, __HIP_MEMORY_SCOPE_WORKGROUP) >= tgt) return;
    do { __builtin_amdgcn_s_sleep(1); }
    while (__hip_atomic_load(c, __ATOMIC_ACQUIRE, __HIP_MEMORY_SCOPE_WORKGROUP) < tgt);
}
__device__ __forceinline__ void publish(int* c) {
    if ((threadIdx.x & 63) == 0)   // release fence (lgkmcnt drain) is wave-wide
        (void)__hip_atomic_fetch_add(c, 1, __ATOMIC_RELEASE, __HIP_MEMORY_SCOPE_WORKGROUP);
}

// -------------------------------------------------------------------------
// Decoupled two-group LSTM:
//   c2 group (waves 0..3): step s=0..255, reads h1(s) [ring s&3] + h2(s-1),
//     writes h2(s) [ring s&3]. Waits: cnt2>=4s (own group), cnt1>=4(s+1).
//   c1 group (waves 4..7): step t=0..259, gates for t<=255 read h1(t-1),
//     write h1(t) [ring t&3]; rotated head (U==t&3) computes out col t-4
//     from h2(t-4) [ring t&3]. Waits: cnt1>=4t (own), cnt2>=4(t-3) — the
//     WAR check for ring slot t&3 doubles as the head's data dependency.
// Ring-safety (depth 4): a writer at step n touches slot n&3; all
// concurrent readers are within 3 steps and touch (n-1..n-3)&3 != n&3.
// Numerics identical to the barrier version (same MFMA/activation order).
// -------------------------------------------------------------------------
__launch_bounds__(512, 2)
__global__ void lstm_main(const float* __restrict__ input,
                          const uint4* __restrict__ frags,
                          float* __restrict__ out) {
    __shared__ __align__(16) unsigned int h1r[4][16][36];
    __shared__ __align__(16) unsigned int h2r[4][16][36];
    __shared__ __align__(16) float xb[(TT + 1) * 16];    // [t][b], row TT = 0
    __shared__ int cnt1, cnt2;

    const int tid  = threadIdx.x;
    const int lane = tid & 63;
    const int w    = tid >> 6;
    const int l15  = lane & 15;
    const int q    = lane >> 4;
    const int b0g  = blockIdx.x * NB;
    const bool c2w = (w < 4);
    const int U    = c2w ? w : (w - 4);
    const int uc   = U * 16 + l15;
    const bool uok = (uc < HH);

    for (int i = tid; i < 4 * 16 * 36; i += 512) {
        ((unsigned*)h1r)[i] = 0; ((unsigned*)h2r)[i] = 0;
    }
    for (int c = 0; c < 2; c++) {
        int flat = tid + c * 512;
        int b = flat >> 6, t0 = (flat & 63) * 4;
        float4 v = *(const float4*)&input[(size_t)(b0g + b) * TT + t0];
        xb[(t0 + 0) * 16 + b] = v.x; xb[(t0 + 1) * 16 + b] = v.y;
        xb[(t0 + 2) * 16 + b] = v.z; xb[(t0 + 3) * 16 + b] = v.w;
    }
    if (tid < 16) xb[TT * 16 + tid] = 0.f;
    if (tid == 0) { cnt1 = 0; cnt2 = 0; }
    __syncthreads();
    if (tid < 16) {                         // initial hooks: h1(-1) = ring slot 3
        int b = tid;
        int wi51 = ((25 + 4 * (b >> 1)) & 31) * 2 + 1;   // u=51 (bias col)
        int wi52 = ((26 + 4 * (b >> 1)) & 31) * 2 + 0;   // u=52 (x_hi)
        int wi53 = ((26 + 4 * (b >> 1)) & 31) * 2 + 1;   // u=53 (x_lo)
        ((unsigned short*)&h1r[3][b][0])[wi51] = 0x3C00;  // fp16(1.0)
        float x0 = input[(size_t)(b0g + b) * TT];
        _Float16 xh = (_Float16)x0;
        ((unsigned short*)&h1r[3][b][0])[wi52] = __builtin_bit_cast(unsigned short, xh);
        ((unsigned short*)&h1r[3][b][0])[wi53] = f2h_bits(x0 - (float)xh);
    }

    // weight-stationary fragments (unchanged)
    half8 fr[32];
    if (c2w) {
#pragma unroll
        for (int g = 0; g < 4; g++) {
            int tau = g * 4 + U;
#pragma unroll
            for (int s = 0; s < 4; s++) {
                fr[g * 8 + s * 2 + 0] = __builtin_bit_cast(half8, frags[(64 + (tau * 4 + s) * 2 + 0) * 64 + lane]);
                fr[g * 8 + s * 2 + 1] = __builtin_bit_cast(half8, frags[(64 + (tau * 4 + s) * 2 + 1) * 64 + lane]);
            }
        }
    } else {
#pragma unroll
        for (int g = 0; g < 4; g++) {
            int tau = g * 4 + U;
#pragma unroll
            for (int s = 0; s < 2; s++) {
                fr[g * 4 + s * 2 + 0] = __builtin_bit_cast(half8, frags[((tau * 2 + s) * 2 + 0) * 64 + lane]);
                fr[g * 4 + s * 2 + 1] = __builtin_bit_cast(half8, frags[((tau * 2 + s) * 2 + 1) * 64 + lane]);
            }
        }
#pragma unroll
        for (int s = 0; s < 2; s++) {       // head frags on ALL c1 waves
            fr[16 + s * 2 + 0] = __builtin_bit_cast(half8, frags[(192 + s * 2 + 0) * 64 + lane]);
            fr[16 + s * 2 + 1] = __builtin_bit_cast(half8, frags[(192 + s * 2 + 1) * 64 + lane]);
        }
    }
    floatx4 zacc = {0.f, 0.f, 0.f, 0.f};
    float cst[4] = {0.f, 0.f, 0.f, 0.f};
    const int baseA = (q * 4 + 4 * (l15 >> 1)) & 31;
    const int baseB = (baseA + 16) & 31;

    __syncthreads();

#define GTAIL(DG, FG, SGN)                                                      \
    _Pragma("unroll")                                                           \
    for (int r = 0; r < 4; r++) {                                               \
        float e = exp2_fast(SGN (DG)[r]);                                       \
        (FG)[r] = rcp_fast(1.0f + e);                                           \
    }

    if (c2w) {
        // ---------------- cell2 group: s = 0..255 ----------------
        for (int s = 0; s < TT; ++s) {
            wait_ge(&cnt2, 4 * s);           // peers done step s-1
            wait_ge(&cnt1, 4 * (s + 1));     // h1(s) ready
            const unsigned int* p1 = &h1r[s & 3][l15][0];
            const unsigned int* p2 = &h2r[(s + 3) & 3][l15][0];
            half8 a0 = *(const half8*)(p1 + baseA);
            half8 a1 = *(const half8*)(p1 + baseB);
            half8 a2 = *(const half8*)(p2 + baseA);
            half8 a3 = *(const half8*)(p2 + baseB);
            floatx4 d0, d1, d2, d3;
            d0 = MFMA16F(a0, fr[0],  zacc); d0 = MFMA16F(a0, fr[1],  d0);
            d1 = MFMA16F(a0, fr[8],  zacc); d1 = MFMA16F(a0, fr[9],  d1);
            d2 = MFMA16F(a0, fr[16], zacc); d2 = MFMA16F(a0, fr[17], d2);
            d3 = MFMA16F(a0, fr[24], zacc); d3 = MFMA16F(a0, fr[25], d3);
            d0 = MFMA16F(a1, fr[2],  d0);   d0 = MFMA16F(a1, fr[3],  d0);
            d1 = MFMA16F(a1, fr[10], d1);   d1 = MFMA16F(a1, fr[11], d1);
            d2 = MFMA16F(a1, fr[18], d2);   d2 = MFMA16F(a1, fr[19], d2);
            d3 = MFMA16F(a1, fr[26], d3);   d3 = MFMA16F(a1, fr[27], d3);
            d0 = MFMA16F(a2, fr[4],  d0);   d0 = MFMA16F(a2, fr[5],  d0);
            d1 = MFMA16F(a2, fr[12], d1);   d1 = MFMA16F(a2, fr[13], d1);
            d2 = MFMA16F(a2, fr[20], d2);   d2 = MFMA16F(a2, fr[21], d2);
            d3 = MFMA16F(a2, fr[28], d3);   d3 = MFMA16F(a2, fr[29], d3);
            d0 = MFMA16F(a3, fr[6],  d0);   d0 = MFMA16F(a3, fr[7],  d0);
            d1 = MFMA16F(a3, fr[14], d1);   d1 = MFMA16F(a3, fr[15], d1);
            d2 = MFMA16F(a3, fr[22], d2);   d2 = MFMA16F(a3, fr[23], d2);
            d3 = MFMA16F(a3, fr[30], d3);   d3 = MFMA16F(a3, fr[31], d3);
            floatx4 f0, f1, f2, f3;
            GTAIL(d0, f0, -) GTAIL(d1, f1, -) GTAIL(d2, f2, +) GTAIL(d3, f3, -)
#pragma unroll
            for (int r = 0; r < 4; r++) {
                float tgs = fmaf(-4.0f * L2E, f2[r], 2.0f * L2E);
                float cn  = fmaf(f1[r], cst[r], f0[r] * tgs);
                cst[r] = cn;
                float th = fmaf(-2.0f, rcp_fast(1.0f + exp2_fast(cn)), 1.0f);
                float hv = f3[r] * th;
                hv = uok ? hv : (uc == 51 ? 1.0f : 0.f);
                int bb = q * 4 + r;
                int wi = (((uc >> 1) + 4 * (bb >> 1)) & 31) * 2 + (uc & 1);
                ((unsigned short*)&h2r[s & 3][bb][0])[wi] = f2h_bits(hv);
            }
            publish(&cnt2);
        }
    } else {
        // ---------------- cell1 group (+rotated head): t = 0..259 ----------------
        for (int t = 0; t < TT + 4; ++t) {
            wait_ge(&cnt1, 4 * t);                       // peers done step t-1
            if (t >= 4) wait_ge(&cnt2, 4 * (t - 3));     // WAR slot t&3 + h2(t-4) ready
            if (t >= 4 && U == (t & 3)) {                // head: out col t-4
                const unsigned int* p2 = &h2r[t & 3][l15][0];   // (t-4)&3 == t&3
                half8 a2 = *(const half8*)(p2 + baseA);
                half8 a3 = *(const half8*)(p2 + baseB);
                floatx4 ho;
                ho = MFMA16F(a2, fr[16], zacc); ho = MFMA16F(a2, fr[17], ho);
                ho = MFMA16F(a3, fr[18], ho);   ho = MFMA16F(a3, fr[19], ho);
                if (l15 == 0) {
#pragma unroll
                    for (int r = 0; r < 4; r++)
                        out[(size_t)(b0g + q * 4 + r) * TT + (t - 4)] = ho[r];
                }
            }
            if (t < TT) {                                // cell1 -> h1(t)
                float4 xn = {0.f, 0.f, 0.f, 0.f};
                if (uc >= HH) xn = *(const float4*)&xb[(t + 1) * 16 + q * 4];
                const unsigned int* p1 = &h1r[(t + 3) & 3][l15][0];
                half8 a0 = *(const half8*)(p1 + baseA);
                half8 a1 = *(const half8*)(p1 + baseB);
                floatx4 d0, d1, d2, d3;
                d0 = MFMA16F(a0, fr[0],  zacc); d0 = MFMA16F(a0, fr[1],  d0);
                d1 = MFMA16F(a0, fr[4],  zacc); d1 = MFMA16F(a0, fr[5],  d1);
                d2 = MFMA16F(a0, fr[8],  zacc); d2 = MFMA16F(a0, fr[9],  d2);
                d3 = MFMA16F(a0, fr[12], zacc); d3 = MFMA16F(a0, fr[13], d3);
                d0 = MFMA16F(a1, fr[2],  d0);   d0 = MFMA16F(a1, fr[3],  d0);
                d1 = MFMA16F(a1, fr[6],  d1);   d1 = MFMA16F(a1, fr[7],  d1);
                d2 = MFMA16F(a1, fr[10], d2);   d2 = MFMA16F(a1, fr[11], d2);
                d3 = MFMA16F(a1, fr[14], d3);   d3 = MFMA16F(a1, fr[15], d3);
                floatx4 f0, f1, f2, f3;
                GTAIL(d0, f0, -) GTAIL(d1, f1, -) GTAIL(d2, f2, +) GTAIL(d3, f3, -)
#pragma unroll
                for (int r = 0; r < 4; r++) {
                    float tgs = fmaf(-4.0f * L2E, f2[r], 2.0f * L2E);
                    float cn  = fmaf(f1[r], cst[r], f0[r] * tgs);
                    cst[r] = cn;
                    float th = fmaf(-2.0f, rcp_fast(1.0f + exp2_fast(cn)), 1.0f);
                    float hv = f3[r] * th;
                    hv = uok ? hv
                             : (uc == 51 ? 1.0f
                             : (uc == 52 ? xn[r]
                             : (uc == 53 ? xn[r] - (float)(_Float16)xn[r] : 0.f)));
                    int bb = q * 4 + r;
                    int wi = (((uc >> 1) + 4 * (bb >> 1)) & 31) * 2 + (uc & 1);
                    ((unsigned short*)&h1r[t & 3][bb][0])[wi] = f2h_bits(hv);
                }
            }
            publish(&cnt1);
        }
    }
#undef GTAIL
}

extern "C" void kernel_launch(void* const* d_in, const int* in_sizes, int n_in,
                              void* d_out, int out_size, void* d_ws, size_t ws_size,
                              hipStream_t stream) {
    const float* input = (const float*)d_in[0];
    const float* Wih1  = (const float*)d_in[1];
    const float* Whh1  = (const float*)d_in[2];
    const float* bih1  = (const float*)d_in[3];
    const float* bhh1  = (const float*)d_in[4];
    const float* Wih2  = (const float*)d_in[5];
    const float* Whh2  = (const float*)d_in[6];
    const float* bih2  = (const float*)d_in[7];
    const float* bhh2  = (const float*)d_in[8];
    const float* Wlin  = (const float*)d_in[9];
    const float* blin  = (const float*)d_in[10];

    uint4* frags = (uint4*)d_ws;            // 196 frags * 1 KiB
    int B = in_sizes[0] / TT;               // 4096

    lstm_prep<<<49, 256, 0, stream>>>(Whh1, Wih1, bih1, bhh1, Wih2, Whh2,
                                      bih2, bhh2, Wlin, blin, frags);
    lstm_main<<<B / NB, 512, 0, stream>>>(input, frags, (float*)d_out);
}